// Round 14
// baseline (78.568 us; speedup 1.0000x reference)
//
#include <hip/hip_runtime.h>
#include <hip/hip_bf16.h>

#define LOG2E 1.4426950408889634f
#define C2    (2.0f * LOG2E)

static __device__ __forceinline__ float fast_exp2(float x) {
#if __has_builtin(__builtin_amdgcn_exp2f)
  return __builtin_amdgcn_exp2f(x);
#else
  return exp2f(x);
#endif
}
static __device__ __forceinline__ float fast_rcp(float x) {
#if __has_builtin(__builtin_amdgcn_rcpf)
  return __builtin_amdgcn_rcpf(x);
#else
  return 1.0f / x;
#endif
}

typedef short bf16x8 __attribute__((ext_vector_type(8)));
typedef float f32x4  __attribute__((ext_vector_type(4)));

static __device__ __forceinline__ short f2bf(float x) {  // RNE f32->bf16
  unsigned u = __float_as_uint(x);
  u += 0x7fff + ((u >> 16) & 1);
  return (short)(u >> 16);
}

// ---------------------------------------------------------------------------
// MFMA projections (r12, unchanged).
//   bz=0: qs[q][h]  = exp2(C2 * (queries@W_q)[q][h])   (row-major Eq)
//   bz=1: ks_p[((b*64+h/4)*256+k)*4 + h%4] = exp2(C2*(keys@W_k)) (packed Ek)
// ---------------------------------------------------------------------------
__global__ __launch_bounds__(256, 4) void proj_kernel(
    const float* __restrict__ queries, const float* __restrict__ keys,
    const float* __restrict__ W_q,     const float* __restrict__ W_k,
    const int*   __restrict__ vlen,
    float* __restrict__ qs, float* __restrict__ ks_p)
{
  const int bz = blockIdx.z;
  const float* X = bz ? keys : queries;
  const float* W = bz ? W_k  : W_q;
  const int n0 = blockIdx.x * 16;
  const int m0 = blockIdx.y * 64;

  if (bz == 1) {                      // masked key tiles: skip whole block
    const int vl = vlen[m0 >> 8];
    if ((m0 & 255) >= vl) return;
  }

  const int t = threadIdx.x;
  const int l = t & 63;
  const int w = t >> 6;

  __shared__ short Wp[8 * 64 * 8];    // [kc][lane][j]  bf16, 8 KB

  {
    const int krow = t >> 2, nseg = t & 3;
#pragma unroll
    for (int p = 0; p < 4; ++p) {
      const int k = p * 64 + krow;
      float4 v = *(const float4*)&W[k * 256 + n0 + nseg * 4];
      const int kc = k >> 5, grp = (k & 31) >> 3, j = k & 7;
      const int lbase = grp * 16 + nseg * 4;
      Wp[(kc * 64 + lbase + 0) * 8 + j] = f2bf(v.x);
      Wp[(kc * 64 + lbase + 1) * 8 + j] = f2bf(v.y);
      Wp[(kc * 64 + lbase + 2) * 8 + j] = f2bf(v.z);
      Wp[(kc * 64 + lbase + 3) * 8 + j] = f2bf(v.w);
    }
  }
  __syncthreads();

  const int mb   = m0 + w * 16;
  const int row  = mb + (l & 15);
  const int kofs = (l >> 4) * 8;

  f32x4 acc = {0.f, 0.f, 0.f, 0.f};
#pragma unroll
  for (int kc = 0; kc < 8; ++kc) {
    float4 a0 = *(const float4*)&X[(size_t)row * 256 + kc * 32 + kofs];
    float4 a1 = *(const float4*)&X[(size_t)row * 256 + kc * 32 + kofs + 4];
    bf16x8 af;
    af[0] = f2bf(a0.x); af[1] = f2bf(a0.y); af[2] = f2bf(a0.z); af[3] = f2bf(a0.w);
    af[4] = f2bf(a1.x); af[5] = f2bf(a1.y); af[6] = f2bf(a1.z); af[7] = f2bf(a1.w);
    bf16x8 bfv = *(bf16x8*)&Wp[(kc * 64 + l) * 8];
    acc = __builtin_amdgcn_mfma_f32_16x16x32_bf16(af, bfv, acc, 0, 0, 0);
  }

  const int c = l & 15;
#pragma unroll
  for (int j = 0; j < 4; ++j) {
    const int rj = (l >> 4) * 4 + j;
    const float o = fast_exp2(acc[j] * C2);
    if (bz == 0) {
      qs[(size_t)(mb + rj) * 256 + n0 + c] = o;
    } else {
      const int b  = mb >> 8;
      const int kl = (mb & 255) + rj;
      ks_p[((size_t)(b * 64 + ((n0 + c) >> 2)) * 256 + kl) * 4 + (c & 3)] = o;
    }
  }
}

// ---------------------------------------------------------------------------
// Score phase, NJ = active 64-wide k-groups (compile-time).
// 8 h-chunks of 32h; each chunk's Ek slice (NJ x 8 KB, contiguous in the
// packed layout) is cooperatively staged into LDS, DOUBLE-BUFFERED with the
// async-stage split: issue next chunk's global b128 loads BEFORE compute,
// ds_write them AFTER (the ~2000cy/SIMD of trans work hides L2 latency).
// Wave w computes h4 = c*8 + w within chunk c (union over c,w = all 64 h4,
// h4 == w mod 8) reading conflict-free b128 from LDS (~120cy vs ~300cy L2).
// One barrier per chunk.  Per elem: t = fma(eq,ek,1); s = fma(wv,rcp(t),s).
// ---------------------------------------------------------------------------
#define SC_STEP(c)                                                         \
  sc[j][0] = fmaf(wv.c, fast_rcp(fmaf(qv0.c, kv[j].c, 1.f)), sc[j][0]);    \
  sc[j][1] = fmaf(wv.c, fast_rcp(fmaf(qv1.c, kv[j].c, 1.f)), sc[j][1]);    \
  sc[j][2] = fmaf(wv.c, fast_rcp(fmaf(qv2.c, kv[j].c, 1.f)), sc[j][2]);    \
  sc[j][3] = fmaf(wv.c, fast_rcp(fmaf(qv3.c, kv[j].c, 1.f)), sc[j][3]);

template <int NJ>
__device__ __forceinline__ void score_phase(
    const float* __restrict__ kp_b,   // ks_p + b*65536
    const float* __restrict__ qp,     // qs + (b*256+q0)*256 (4 rows, uniform)
    const float* __restrict__ wvp,
    const int lane, const int w, float* __restrict__ lds,
    float (&sc)[4][4])
{
  float* const buf0 = lds;
  float* const buf1 = lds + NJ * 2048;
  const int rbase = (w * NJ) * 256 + lane * 4;   // this thread's LDS slot

  // prologue: stage chunk 0 (this thread's h4-row = w)
  {
    const float* src = kp_b + (size_t)w * 1024 + lane * 4;
#pragma unroll
    for (int j = 0; j < NJ; ++j) {
      float4 r = *(const float4*)(src + j * 256);
      *(float4*)&buf0[rbase + j * 256] = r;
    }
  }
  __syncthreads();

#pragma unroll
  for (int c = 0; c < 8; ++c) {
    float* const bufc = (c & 1) ? buf1 : buf0;
    float* const bufn = (c & 1) ? buf0 : buf1;

    float4 nxt[NJ];
    if (c < 7) {                       // issue next chunk's loads EARLY
      const float* src = kp_b + (size_t)((c + 1) * 8 + w) * 1024 + lane * 4;
#pragma unroll
      for (int j = 0; j < NJ; ++j) nxt[j] = *(const float4*)(src + j * 256);
    }

    const int h4 = c * 8 + w;
    float4 qv0 = *(const float4*)(qp + 0 * 256 + h4 * 4);  // uniform s_loads
    float4 qv1 = *(const float4*)(qp + 1 * 256 + h4 * 4);
    float4 qv2 = *(const float4*)(qp + 2 * 256 + h4 * 4);
    float4 qv3 = *(const float4*)(qp + 3 * 256 + h4 * 4);
    float4 wv  = *(const float4*)(wvp + h4 * 4);
    float4 kv[NJ];
#pragma unroll
    for (int j = 0; j < NJ; ++j)
      kv[j] = *(const float4*)&bufc[rbase + j * 256];
#pragma unroll
    for (int j = 0; j < NJ; ++j) {
      SC_STEP(x); SC_STEP(y); SC_STEP(z); SC_STEP(w);
    }

    if (c < 7) {                       // write next chunk LATE (loads landed)
#pragma unroll
      for (int j = 0; j < NJ; ++j)
        *(float4*)&bufn[rbase + j * 256] = nxt[j];
    }
    __syncthreads();
  }
}

// ---------------------------------------------------------------------------
// Fused scores + softmax + PV, v9: LDS-staged score k-path.
// Grid: 512 = 8 batches x 64 4q-tiles (batch-interleaved); block: 512 thr
// = 8 waves -> 2 blocks/CU (LDS 69.7 KB), 4 waves/SIMD.  Softmax: waves
// 0-3 own one q-row each.  PV: wave w takes k == w (mod 8), 4 q-accums per
// V load, depth-1 prefetch.  LDS regions: [0,16384) staging double-buffer,
// reused for score partials then PV partials; p2 at 16384; rsum at 17408.
// ---------------------------------------------------------------------------
__global__ __launch_bounds__(512, 4) void attn_kernel(
    const float* __restrict__ qs, const float* __restrict__ ks_p,
    const float* __restrict__ values, const int* __restrict__ vlen,
    const float* __restrict__ w_v, float* __restrict__ out)
{
  const int t    = threadIdx.x;
  const int lane = t & 63;
  const int w    = t >> 6;                 // wave 0..7
  const int bx   = blockIdx.x;
  const int b    = ((bx & 7) + (bx >> 6)) & 7;
  const int q0   = (bx >> 3) * 4;

  __shared__ __align__(16) float lds[16384 + 1024 + 16];   // 69.7 KB
  float* const sbuf = lds;                  // 32 KB partials (aliases staging)
  float* const p2   = lds + 16384;          // 4 KB [k][q]
  float* const rsum_lds = lds + 17408;

  const int vl = vlen[b];
  const int nj = (vl + 63) >> 6;

  // Wsum = sum(w_v)
  float s0 = w_v[lane] + w_v[lane + 64] + w_v[lane + 128] + w_v[lane + 192];
#pragma unroll
  for (int off = 32; off; off >>= 1) s0 += __shfl_xor(s0, off);
  const float Wsum = s0;

  const float* qp   = qs + (size_t)(b * 256 + q0) * 256;   // 4 rows, uniform
  const float* kp_b = ks_p + (size_t)b * 65536;

  float sc[4][4] = {};
  switch (nj) {
    case 1:  score_phase<1>(kp_b, qp, w_v, lane, w, lds, sc); break;
    case 2:  score_phase<2>(kp_b, qp, w_v, lane, w, lds, sc); break;
    case 3:  score_phase<3>(kp_b, qp, w_v, lane, w, lds, sc); break;
    default: score_phase<4>(kp_b, qp, w_v, lane, w, lds, sc); break;
  }
  // (score_phase ends with __syncthreads -> staging buffers dead)

  // write partials: sbuf[((w*4 + j)*64 + lane)*4 + q]  (b128, conflict-free)
#pragma unroll
  for (int j = 0; j < 4; ++j)
    *(float4*)&sbuf[((w * 4 + j) * 64 + lane) * 4] =
        make_float4(sc[j][0], sc[j][1], sc[j][2], sc[j][3]);
  __syncthreads();

  // softmax: waves 0-3, wave q owns q-row q0+q
  if (w < 4) {
    const int q = w;
    float scores[4];
    float mx = -3.4e38f;
#pragma unroll 4
    for (int j = 0; j < nj; ++j) {
      float s = 0.f;
#pragma unroll
      for (int ww = 0; ww < 8; ++ww)
        s += sbuf[((ww * 4 + j) * 64 + lane) * 4 + q];
      float v = Wsum - 2.f * s;
      if (j * 64 + lane >= vl) v = -1000000.0f;
      scores[j] = v;
      mx = fmaxf(mx, v);
    }
#pragma unroll
    for (int off = 32; off; off >>= 1) mx = fmaxf(mx, __shfl_xor(mx, off));
    float sum = 0.f;
#pragma unroll 4
    for (int j = 0; j < nj; ++j) {
      float p = fast_exp2((scores[j] - mx) * LOG2E);
      p2[(j * 64 + lane) * 4 + q] = p;
      sum += p;
    }
#pragma unroll
    for (int off = 32; off; off >>= 1) sum += __shfl_xor(sum, off);
    if (lane == 0) rsum_lds[q] = sum;
  }
  __syncthreads();                        // sbuf reads done; p2/rsum ready

  // PV: wave w takes k == w (mod 8); 4 q-accums per V load; depth-1 prefetch
  float4 acc[4];
#pragma unroll
  for (int q = 0; q < 4; ++q) acc[q] = make_float4(0.f, 0.f, 0.f, 0.f);
  const float* Vb = values + (size_t)b * 65536 + lane * 4;
  if (w < vl) {
    float4 v = *(const float4*)(Vb + (size_t)w * 256);
    for (int k = w; k < vl; k += 8) {
      float4 vn = v;
      if (k + 8 < vl) vn = *(const float4*)(Vb + (size_t)(k + 8) * 256);
      float4 pk = *(const float4*)&p2[k * 4];        // b128 LDS broadcast
      acc[0].x = fmaf(pk.x, v.x, acc[0].x);
      acc[0].y = fmaf(pk.x, v.y, acc[0].y);
      acc[0].z = fmaf(pk.x, v.z, acc[0].z);
      acc[0].w = fmaf(pk.x, v.w, acc[0].w);
      acc[1].x = fmaf(pk.y, v.x, acc[1].x);
      acc[1].y = fmaf(pk.y, v.y, acc[1].y);
      acc[1].z = fmaf(pk.y, v.z, acc[1].z);
      acc[1].w = fmaf(pk.y, v.w, acc[1].w);
      acc[2].x = fmaf(pk.z, v.x, acc[2].x);
      acc[2].y = fmaf(pk.z, v.y, acc[2].y);
      acc[2].z = fmaf(pk.z, v.z, acc[2].z);
      acc[2].w = fmaf(pk.z, v.w, acc[2].w);
      acc[3].x = fmaf(pk.w, v.x, acc[3].x);
      acc[3].y = fmaf(pk.w, v.y, acc[3].y);
      acc[3].z = fmaf(pk.w, v.z, acc[3].z);
      acc[3].w = fmaf(pk.w, v.w, acc[3].w);
      v = vn;
    }
  }
  // PV partials reuse sbuf: [w][q][256]
#pragma unroll
  for (int q = 0; q < 4; ++q)
    *(float4*)&sbuf[(w * 4 + q) * 256 + lane * 4] = acc[q];
  __syncthreads();

  // final reduce: 512 thr x 2 -> 4q x 256d
#pragma unroll
  for (int rep = 0; rep < 2; ++rep) {
    int o = t + rep * 512;
    int q = o >> 8, d = o & 255;
    float s = 0.f;
#pragma unroll
    for (int ww = 0; ww < 8; ++ww) s += sbuf[(ww * 4 + q) * 256 + d];
    out[(size_t)(b * 256 + q0 + q) * 256 + d] = s * fast_rcp(rsum_lds[q]);
  }
}

extern "C" void kernel_launch(void* const* d_in, const int* in_sizes, int n_in,
                              void* d_out, int out_size, void* d_ws, size_t ws_size,
                              hipStream_t stream) {
  const float* queries = (const float*)d_in[0];
  const float* keys    = (const float*)d_in[1];
  const float* values  = (const float*)d_in[2];
  const int*   vlenp   = (const int*)d_in[3];
  const float* W_q     = (const float*)d_in[4];
  const float* W_k     = (const float*)d_in[5];
  const float* w_v     = (const float*)d_in[6];
  float* out = (float*)d_out;

  float* qs   = (float*)d_ws;               // 2 MiB, Eq row-major [m][256]
  float* ks_p = qs + 2048 * 256;            // 2 MiB, Ek packed [b][h/4][k][4]

  dim3 pgrid(16, 32, 2);                    // (n-strips, m-tiles, matrix)
  proj_kernel<<<pgrid, 256, 0, stream>>>(queries, keys, W_q, W_k, vlenp, qs, ks_p);
  attn_kernel<<<512, 512, 0, stream>>>(qs, ks_p, values, vlenp, w_v, out);
}

// Round 16
// 46.458 us; speedup vs baseline: 1.6912x; 1.6912x over previous
//
#include <hip/hip_runtime.h>
#include <hip/hip_bf16.h>
#include <hip/hip_fp16.h>

#define LOG2E 1.4426950408889634f
#define C2    (2.0f * LOG2E)

static __device__ __forceinline__ float fast_exp2(float x) {
#if __has_builtin(__builtin_amdgcn_exp2f)
  return __builtin_amdgcn_exp2f(x);
#else
  return exp2f(x);
#endif
}
static __device__ __forceinline__ float fast_rcp(float x) {
#if __has_builtin(__builtin_amdgcn_rcpf)
  return __builtin_amdgcn_rcpf(x);
#else
  return 1.0f / x;
#endif
}

typedef short bf16x8 __attribute__((ext_vector_type(8)));
typedef float f32x4  __attribute__((ext_vector_type(4)));

static __device__ __forceinline__ short f2bf(float x) {  // RNE f32->bf16
  unsigned u = __float_as_uint(x);
  u += 0x7fff + ((u >> 16) & 1);
  return (short)(u >> 16);
}
static __device__ __forceinline__ float bf2f(unsigned short u) {
  return __uint_as_float((unsigned)u << 16);
}

// ---------------------------------------------------------------------------
// MFMA projections (r12 structure).
//   bz=0: qs[q][h] = exp2(C2*(queries@W_q))      f32 row-major (Eq)
//   bz=1: ks_pb[((b*64+h/4)*256+k)*4 + h%4] = bf16(exp2(C2*(keys@W_k)))  (Ek)
// Ek stored BF16: halves score-phase k-traffic; rel err ~0.4% on a
// tanh-bounded term — well inside the 1.5e-2 threshold margin.
// ---------------------------------------------------------------------------
__global__ __launch_bounds__(256, 4) void proj_kernel(
    const float* __restrict__ queries, const float* __restrict__ keys,
    const float* __restrict__ W_q,     const float* __restrict__ W_k,
    const int*   __restrict__ vlen,
    float* __restrict__ qs, unsigned short* __restrict__ ks_pb)
{
  const int bz = blockIdx.z;
  const float* X = bz ? keys : queries;
  const float* W = bz ? W_k  : W_q;
  const int n0 = blockIdx.x * 16;
  const int m0 = blockIdx.y * 64;

  if (bz == 1) {                      // masked key tiles (64-row = chunk
    const int vl = vlen[m0 >> 8];     // granularity): skip whole block;
    if ((m0 & 255) >= vl) return;     // stale data never read downstream
  }

  const int t = threadIdx.x;
  const int l = t & 63;
  const int w = t >> 6;

  __shared__ short Wp[8 * 64 * 8];    // [kc][lane][j]  bf16, 8 KB

  {
    const int krow = t >> 2, nseg = t & 3;
#pragma unroll
    for (int p = 0; p < 4; ++p) {
      const int k = p * 64 + krow;
      float4 v = *(const float4*)&W[k * 256 + n0 + nseg * 4];
      const int kc = k >> 5, grp = (k & 31) >> 3, j = k & 7;
      const int lbase = grp * 16 + nseg * 4;
      Wp[(kc * 64 + lbase + 0) * 8 + j] = f2bf(v.x);
      Wp[(kc * 64 + lbase + 1) * 8 + j] = f2bf(v.y);
      Wp[(kc * 64 + lbase + 2) * 8 + j] = f2bf(v.z);
      Wp[(kc * 64 + lbase + 3) * 8 + j] = f2bf(v.w);
    }
  }
  __syncthreads();

  const int mb   = m0 + w * 16;
  const int row  = mb + (l & 15);
  const int kofs = (l >> 4) * 8;

  f32x4 acc = {0.f, 0.f, 0.f, 0.f};
#pragma unroll
  for (int kc = 0; kc < 8; ++kc) {
    float4 a0 = *(const float4*)&X[(size_t)row * 256 + kc * 32 + kofs];
    float4 a1 = *(const float4*)&X[(size_t)row * 256 + kc * 32 + kofs + 4];
    bf16x8 af;
    af[0] = f2bf(a0.x); af[1] = f2bf(a0.y); af[2] = f2bf(a0.z); af[3] = f2bf(a0.w);
    af[4] = f2bf(a1.x); af[5] = f2bf(a1.y); af[6] = f2bf(a1.z); af[7] = f2bf(a1.w);
    bf16x8 bfv = *(bf16x8*)&Wp[(kc * 64 + l) * 8];
    acc = __builtin_amdgcn_mfma_f32_16x16x32_bf16(af, bfv, acc, 0, 0, 0);
  }

  const int c = l & 15;
#pragma unroll
  for (int j = 0; j < 4; ++j) {
    const int rj = (l >> 4) * 4 + j;
    const float o = fast_exp2(acc[j] * C2);
    if (bz == 0) {
      qs[(size_t)(mb + rj) * 256 + n0 + c] = o;
    } else {
      const int b  = mb >> 8;
      const int kl = (mb & 255) + rj;
      ks_pb[((size_t)(b * 64 + ((n0 + c) >> 2)) * 256 + kl) * 4 + (c & 3)] =
          (unsigned short)f2bf(o);
    }
  }
}

// ---------------------------------------------------------------------------
// scorepv: one block per UNIT (b, g = 4q-tile, c = 64-k chunk, c < nj(b)).
// No-max softmax (|score| <= sum|w_v| ~ 8 -> exp always finite) makes the
// chunk decomposition associative: each unit writes its chunk's partial
// denominator and f16 PV-numerator ONCE (no atomics, no zeroing).
// Grid 2048 = all (b,g,c); inactive (c >= nj) exit before any LDS/barrier.
// bx->(b,c,g) bit-mix: each CU's 8 round-robin slots sample different
// (b,c) -> active blocks/CU ~ 5 +- 1 for any vlen draw (no nj tail).
// Block: 256 thr = 4 waves = h-quarters; 16 iters x {1 b64 bf16 k-load +
// 4 uniform q s_loads + 16 rcp + 32 fma}.  Then exp + denom + PV partial.
// ---------------------------------------------------------------------------
__global__ __launch_bounds__(256, 8) void scorepv_kernel(
    const float* __restrict__ qs, const unsigned short* __restrict__ ks_pb,
    const float* __restrict__ values, const int* __restrict__ vlen,
    const float* __restrict__ w_v,
    __half* __restrict__ numer, float* __restrict__ denom)
{
  const unsigned u  = blockIdx.x;
  const int hi = u >> 8;
  const int c  = (int)(u ^ hi) & 3;
  const int b  = (((int)(u >> 2) & 7) + hi) & 7;
  const int g  = (int)(u >> 5) & 63;

  const int vl = vlen[b];
  const int nj = (vl + 63) >> 6;
  if (c >= nj) return;                    // block-uniform exit (pre-barrier)

  const int t    = threadIdx.x;
  const int lane = t & 63;
  const int w    = t >> 6;                // h-quarter / q-row / k-parity

  __shared__ __align__(16) float sbuf[4 * 64 * 4];   // 4 KB score exchange
  __shared__ __align__(16) float p2[64 * 4];         // 1 KB [k][q]
  __shared__ __align__(16) float pbuf[4 * 4 * 256];  // 16 KB PV partials

  // Wsum = sum(w_v)
  float s0 = w_v[lane] + w_v[lane + 64] + w_v[lane + 128] + w_v[lane + 192];
#pragma unroll
  for (int off = 32; off; off >>= 1) s0 += __shfl_xor(s0, off);
  const float Wsum = s0;

  const float* qp = qs + (size_t)(b * 256 + g * 4) * 256;   // 4 rows, uniform
  const int k = c * 64 + lane;
  const unsigned short* kp = ks_pb + ((size_t)b * 64 * 256 + k) * 4;

  float sc[4] = {0.f, 0.f, 0.f, 0.f};
#pragma unroll 4
  for (int h4 = w * 16; h4 < w * 16 + 16; ++h4) {
    ushort4 kb = *(const ushort4*)(kp + (size_t)h4 * 1024);
    const float kx = bf2f(kb.x), ky = bf2f(kb.y),
                kz = bf2f(kb.z), kw = bf2f(kb.w);
    float4 qv0 = *(const float4*)(qp + 0 * 256 + h4 * 4);   // uniform s_loads
    float4 qv1 = *(const float4*)(qp + 1 * 256 + h4 * 4);
    float4 qv2 = *(const float4*)(qp + 2 * 256 + h4 * 4);
    float4 qv3 = *(const float4*)(qp + 3 * 256 + h4 * 4);
    float4 wv  = *(const float4*)(w_v + h4 * 4);
    sc[0] = fmaf(wv.x, fast_rcp(fmaf(qv0.x, kx, 1.f)), sc[0]);
    sc[1] = fmaf(wv.x, fast_rcp(fmaf(qv1.x, kx, 1.f)), sc[1]);
    sc[2] = fmaf(wv.x, fast_rcp(fmaf(qv2.x, kx, 1.f)), sc[2]);
    sc[3] = fmaf(wv.x, fast_rcp(fmaf(qv3.x, kx, 1.f)), sc[3]);
    sc[0] = fmaf(wv.y, fast_rcp(fmaf(qv0.y, ky, 1.f)), sc[0]);
    sc[1] = fmaf(wv.y, fast_rcp(fmaf(qv1.y, ky, 1.f)), sc[1]);
    sc[2] = fmaf(wv.y, fast_rcp(fmaf(qv2.y, ky, 1.f)), sc[2]);
    sc[3] = fmaf(wv.y, fast_rcp(fmaf(qv3.y, ky, 1.f)), sc[3]);
    sc[0] = fmaf(wv.z, fast_rcp(fmaf(qv0.z, kz, 1.f)), sc[0]);
    sc[1] = fmaf(wv.z, fast_rcp(fmaf(qv1.z, kz, 1.f)), sc[1]);
    sc[2] = fmaf(wv.z, fast_rcp(fmaf(qv2.z, kz, 1.f)), sc[2]);
    sc[3] = fmaf(wv.z, fast_rcp(fmaf(qv3.z, kz, 1.f)), sc[3]);
    sc[0] = fmaf(wv.w, fast_rcp(fmaf(qv0.w, kw, 1.f)), sc[0]);
    sc[1] = fmaf(wv.w, fast_rcp(fmaf(qv1.w, kw, 1.f)), sc[1]);
    sc[2] = fmaf(wv.w, fast_rcp(fmaf(qv2.w, kw, 1.f)), sc[2]);
    sc[3] = fmaf(wv.w, fast_rcp(fmaf(qv3.w, kw, 1.f)), sc[3]);
  }
  *(float4*)&sbuf[(w * 64 + lane) * 4] = make_float4(sc[0], sc[1], sc[2], sc[3]);
  __syncthreads();

  // combine h-quarters, exp (NO max subtraction), chunk denominator
  {
    float s = sbuf[(0 * 64 + lane) * 4 + w] + sbuf[(1 * 64 + lane) * 4 + w] +
              sbuf[(2 * 64 + lane) * 4 + w] + sbuf[(3 * 64 + lane) * 4 + w];
    float v = Wsum - 2.f * s;                    // |v| <= ~8 -> exp finite
    float p = (k < vl) ? fast_exp2(v * LOG2E) : 0.f;
    p2[lane * 4 + w] = p;
    float ps = p;
#pragma unroll
    for (int off = 32; off; off >>= 1) ps += __shfl_xor(ps, off);
    if (lane == 0) denom[(size_t)c * 2048 + b * 256 + g * 4 + w] = ps;
  }
  __syncthreads();

  // PV partial over this chunk: wave w takes kk == w (mod 4)
  const int nk = min(64, vl - c * 64);
  float4 acc[4];
#pragma unroll
  for (int q = 0; q < 4; ++q) acc[q] = make_float4(0.f, 0.f, 0.f, 0.f);
  const float* Vb = values + (size_t)(b * 256 + c * 64) * 256 + lane * 4;
  for (int kk = w; kk < nk; kk += 4) {
    float4 p4 = *(const float4*)&p2[kk * 4];      // b128 broadcast
    float4 vv = *(const float4*)(Vb + (size_t)kk * 256);
    acc[0].x = fmaf(p4.x, vv.x, acc[0].x);
    acc[0].y = fmaf(p4.x, vv.y, acc[0].y);
    acc[0].z = fmaf(p4.x, vv.z, acc[0].z);
    acc[0].w = fmaf(p4.x, vv.w, acc[0].w);
    acc[1].x = fmaf(p4.y, vv.x, acc[1].x);
    acc[1].y = fmaf(p4.y, vv.y, acc[1].y);
    acc[1].z = fmaf(p4.y, vv.z, acc[1].z);
    acc[1].w = fmaf(p4.y, vv.w, acc[1].w);
    acc[2].x = fmaf(p4.z, vv.x, acc[2].x);
    acc[2].y = fmaf(p4.z, vv.y, acc[2].y);
    acc[2].z = fmaf(p4.z, vv.z, acc[2].z);
    acc[2].w = fmaf(p4.z, vv.w, acc[2].w);
    acc[3].x = fmaf(p4.w, vv.x, acc[3].x);
    acc[3].y = fmaf(p4.w, vv.y, acc[3].y);
    acc[3].z = fmaf(p4.w, vv.z, acc[3].z);
    acc[3].w = fmaf(p4.w, vv.w, acc[3].w);
  }
#pragma unroll
  for (int q = 0; q < 4; ++q)
    *(float4*)&pbuf[(w * 4 + q) * 256 + lane * 4] = acc[q];
  __syncthreads();

  // combine 4 k-parity waves -> f16 slab write (write-once, no atomics)
  {
    const int q = t >> 6, d0 = (t & 63) * 4;
    float4 s4 = make_float4(0.f, 0.f, 0.f, 0.f);
#pragma unroll
    for (int ww = 0; ww < 4; ++ww) {
      float4 v = *(const float4*)&pbuf[(ww * 4 + q) * 256 + d0];
      s4.x += v.x; s4.y += v.y; s4.z += v.z; s4.w += v.w;
    }
    __half* np = numer + ((size_t)c * 2048 + b * 256 + g * 4 + q) * 256 + d0;
    short4 st;
    st.x = (short)__half_as_ushort(__float2half(s4.x));
    st.y = (short)__half_as_ushort(__float2half(s4.y));
    st.z = (short)__half_as_ushort(__float2half(s4.z));
    st.w = (short)__half_as_ushort(__float2half(s4.w));
    *(short4*)np = st;
  }
}

// ---------------------------------------------------------------------------
// finalize: out[r][d] = sum_{c<nj} numer[c][r][d] / sum_{c<nj} denom[c][r].
// Grid 512 x 256thr; thread -> (row r0+t/64, d = (t&63)*4 .. +3).
// ---------------------------------------------------------------------------
__global__ __launch_bounds__(256) void finalize_kernel(
    const __half* __restrict__ numer, const float* __restrict__ denom,
    const int* __restrict__ vlen, float* __restrict__ out)
{
  const int t  = threadIdx.x;
  const int r  = blockIdx.x * 4 + (t >> 6);
  const int d0 = (t & 63) * 4;
  const int b  = r >> 8;
  const int nj = (vlen[b] + 63) >> 6;

  float den = 0.f;
  float4 s = make_float4(0.f, 0.f, 0.f, 0.f);
#pragma unroll 4
  for (int c = 0; c < nj; ++c) {
    den += denom[(size_t)c * 2048 + r];
    ushort4 nv = *(const ushort4*)(numer + ((size_t)c * 2048 + r) * 256 + d0);
    s.x += __half2float(__ushort_as_half(nv.x));
    s.y += __half2float(__ushort_as_half(nv.y));
    s.z += __half2float(__ushort_as_half(nv.z));
    s.w += __half2float(__ushort_as_half(nv.w));
  }
  const float rin = fast_rcp(den);
  *(float4*)&out[(size_t)r * 256 + d0] =
      make_float4(s.x * rin, s.y * rin, s.z * rin, s.w * rin);
}

extern "C" void kernel_launch(void* const* d_in, const int* in_sizes, int n_in,
                              void* d_out, int out_size, void* d_ws, size_t ws_size,
                              hipStream_t stream) {
  const float* queries = (const float*)d_in[0];
  const float* keys    = (const float*)d_in[1];
  const float* values  = (const float*)d_in[2];
  const int*   vlenp   = (const int*)d_in[3];
  const float* W_q     = (const float*)d_in[4];
  const float* W_k     = (const float*)d_in[5];
  const float* w_v     = (const float*)d_in[6];
  float* out = (float*)d_out;

  // ws layout (7.03 MiB total; harness workspace proved >= 8 MiB in r8):
  float*          qs    = (float*)d_ws;                                   // 2 MiB Eq f32
  unsigned short* ks_pb = (unsigned short*)((char*)d_ws + ((size_t)2 << 20)); // 1 MiB Ek bf16
  __half* numer = (__half*)((char*)d_ws + ((size_t)3 << 20));             // 4 MiB f16
  float*  denom = (float*)((char*)d_ws + ((size_t)7 << 20));              // 32 KiB f32

  dim3 pgrid(16, 32, 2);                    // (n-strips, m-tiles, matrix)
  proj_kernel<<<pgrid, 256, 0, stream>>>(queries, keys, W_q, W_k, vlenp, qs, ks_pb);
  scorepv_kernel<<<2048, 256, 0, stream>>>(qs, ks_pb, values, vlenp, w_v,
                                           numer, denom);
  finalize_kernel<<<512, 256, 0, stream>>>(numer, denom, vlenp, out);
}

// Round 17
// 35.948 us; speedup vs baseline: 2.1856x; 1.2924x over previous
//
#include <hip/hip_runtime.h>
#include <hip/hip_bf16.h>

#define LOG2E 1.4426950408889634f
#define C2    (2.0f * LOG2E)

static __device__ __forceinline__ float fast_exp2(float x) {
#if __has_builtin(__builtin_amdgcn_exp2f)
  return __builtin_amdgcn_exp2f(x);
#else
  return exp2f(x);
#endif
}
static __device__ __forceinline__ float fast_rcp(float x) {
#if __has_builtin(__builtin_amdgcn_rcpf)
  return __builtin_amdgcn_rcpf(x);
#else
  return 1.0f / x;
#endif
}

typedef short bf16x8 __attribute__((ext_vector_type(8)));
typedef float f32x4  __attribute__((ext_vector_type(4)));

static __device__ __forceinline__ short f2bf(float x) {  // RNE f32->bf16
  unsigned u = __float_as_uint(x);
  u += 0x7fff + ((u >> 16) & 1);
  return (short)(u >> 16);
}

// ---------------------------------------------------------------------------
// MFMA projections v2: 64m x 32n per block (was 64x16).
//   bz=0: qs[q][h] = exp2(C2*(queries@W_q))   f32 row-major (Eq)
//   bz=1: ks_p[((b*64+h/4)*256+k)*4 + h%4] = exp2(C2*(keys@W_k))  (Ek, f32)
// Block: 256 thr = 4 waves; wave w owns rows [m0+w*16, +16) x 32 n
//   = 2 independent MFMA chains (ILP x2), 8 k-steps each.
// W staged once (16 KB bf16) in fragment order with COALESCED dword global
// reads + one ds_write_b128 per 8 k (was 64 scattered b16 writes/thread).
// Grid (8 n-strips, 32 m-tiles, 2) = 512 blocks -> 2/CU.
// A/B share the same assumed k-map (permutation cancels); C/D map verified
// in r12 (col=lane&15, row=(lane>>4)*4+reg).
// ---------------------------------------------------------------------------
__global__ __launch_bounds__(256, 4) void proj_kernel(
    const float* __restrict__ queries, const float* __restrict__ keys,
    const float* __restrict__ W_q,     const float* __restrict__ W_k,
    const int*   __restrict__ vlen,
    float* __restrict__ qs, float* __restrict__ ks_p)
{
  const int bz = blockIdx.z;
  const float* X = bz ? keys : queries;
  const float* W = bz ? W_k  : W_q;
  const int n0 = blockIdx.x * 32;
  const int m0 = blockIdx.y * 64;

  if (bz == 1) {                      // masked key tiles: skip whole block
    const int vl = vlen[m0 >> 8];
    if ((m0 & 255) >= vl) return;
  }

  const int t = threadIdx.x;
  const int l = t & 63;
  const int w = t >> 6;

  __shared__ short Wp[8 * 2 * 64 * 8];   // [kc][nt][lane][j] bf16, 16 KB

  // stage W[k][n0..n0+32) -> fragment order.
  // thread t: nl = t&31 (local n), ko = t>>5; rep over k-octs ko+8*rep.
  // global reads: for fixed jj, 32 consecutive nl -> coalesced dwords.
  {
    const int nl = t & 31, ko = t >> 5;
#pragma unroll
    for (int rep = 0; rep < 4; ++rep) {
      const int koct = ko + rep * 8;        // 0..31, k = koct*8 + jj
      const int kc  = koct >> 2;
      const int grp = koct & 3;
      const int nt  = nl >> 4;
      const int ln  = grp * 16 + (nl & 15);
      short w8[8];
#pragma unroll
      for (int jj = 0; jj < 8; ++jj)
        w8[jj] = f2bf(W[(size_t)(koct * 8 + jj) * 256 + n0 + nl]);
      *(bf16x8*)&Wp[((kc * 2 + nt) * 64 + ln) * 8] = *(bf16x8*)w8;
    }
  }
  __syncthreads();

  const int mb   = m0 + w * 16;
  const int row  = mb + (l & 15);
  const int kofs = (l >> 4) * 8;

  f32x4 acc0 = {0.f, 0.f, 0.f, 0.f};
  f32x4 acc1 = {0.f, 0.f, 0.f, 0.f};
#pragma unroll
  for (int kc = 0; kc < 8; ++kc) {
    float4 a0 = *(const float4*)&X[(size_t)row * 256 + kc * 32 + kofs];
    float4 a1 = *(const float4*)&X[(size_t)row * 256 + kc * 32 + kofs + 4];
    bf16x8 af;
    af[0] = f2bf(a0.x); af[1] = f2bf(a0.y); af[2] = f2bf(a0.z); af[3] = f2bf(a0.w);
    af[4] = f2bf(a1.x); af[5] = f2bf(a1.y); af[6] = f2bf(a1.z); af[7] = f2bf(a1.w);
    bf16x8 b0 = *(bf16x8*)&Wp[((kc * 2 + 0) * 64 + l) * 8];
    bf16x8 b1 = *(bf16x8*)&Wp[((kc * 2 + 1) * 64 + l) * 8];
    acc0 = __builtin_amdgcn_mfma_f32_16x16x32_bf16(af, b0, acc0, 0, 0, 0);
    acc1 = __builtin_amdgcn_mfma_f32_16x16x32_bf16(af, b1, acc1, 0, 0, 0);
  }

  const int c = l & 15;
#pragma unroll
  for (int nt = 0; nt < 2; ++nt) {
    const f32x4 acc = nt ? acc1 : acc0;
    const int n = n0 + nt * 16 + c;
#pragma unroll
    for (int j = 0; j < 4; ++j) {
      const int rj = (l >> 4) * 4 + j;
      const float o = fast_exp2(acc[j] * C2);
      if (bz == 0) {
        qs[(size_t)(mb + rj) * 256 + n] = o;
      } else {
        const int b  = mb >> 8;
        const int kl = (mb & 255) + rj;
        ks_p[((size_t)(b * 64 + (n >> 2)) * 256 + kl) * 4 + (n & 3)] = o;
      }
    }
  }
}

// ---------------------------------------------------------------------------
// Score inner loop, NJ = active 64-wide k-groups (compile-time).
// Wave = h-EIGHTH (8 h4 iters); each kv b128 load is amortized over FOUR
// q-rows: per elem t = fma(eq, ek, 1); s = fma(w, rcp(t), s).
// ---------------------------------------------------------------------------
#define SC_STEP(c)                                                         \
  sc[j][0] = fmaf(wv.c, fast_rcp(fmaf(qv0.c, kv[j].c, 1.f)), sc[j][0]);    \
  sc[j][1] = fmaf(wv.c, fast_rcp(fmaf(qv1.c, kv[j].c, 1.f)), sc[j][1]);    \
  sc[j][2] = fmaf(wv.c, fast_rcp(fmaf(qv2.c, kv[j].c, 1.f)), sc[j][2]);    \
  sc[j][3] = fmaf(wv.c, fast_rcp(fmaf(qv3.c, kv[j].c, 1.f)), sc[j][3]);

template <int NJ>
__device__ __forceinline__ void score_loop(
    const float* __restrict__ kp,    // ks_p + b*65536 + lane*4
    const float* __restrict__ qp,    // qs + (b*256+q0)*256 (4 rows)
    const float* __restrict__ wvp, int h4b, float (&sc)[4][4])
{
#pragma unroll 2
  for (int h4 = h4b; h4 < h4b + 8; ++h4) {
    float4 kv[NJ];
#pragma unroll
    for (int j = 0; j < NJ; ++j)
      kv[j] = *(const float4*)(kp + h4 * 1024 + j * 256);
    float4 qv0 = *(const float4*)(qp + 0 * 256 + h4 * 4);  // uniform s_loads
    float4 qv1 = *(const float4*)(qp + 1 * 256 + h4 * 4);
    float4 qv2 = *(const float4*)(qp + 2 * 256 + h4 * 4);
    float4 qv3 = *(const float4*)(qp + 3 * 256 + h4 * 4);
    float4 wv  = *(const float4*)(wvp + h4 * 4);
#pragma unroll
    for (int j = 0; j < NJ; ++j) {
      SC_STEP(x); SC_STEP(y); SC_STEP(z); SC_STEP(w);
    }
  }
}

// ---------------------------------------------------------------------------
// Fused scores + softmax + PV (r13, unchanged — best known).
// ---------------------------------------------------------------------------
__global__ __launch_bounds__(512, 4) void attn_kernel(
    const float* __restrict__ qs, const float* __restrict__ ks_p,
    const float* __restrict__ values, const int* __restrict__ vlen,
    const float* __restrict__ w_v, float* __restrict__ out)
{
  const int t    = threadIdx.x;
  const int lane = t & 63;
  const int w    = t >> 6;                 // h-eighth / PV k-parity 0..7
  const int bx   = blockIdx.x;
  const int b    = ((bx & 7) + (bx >> 6)) & 7;
  const int q0   = (bx >> 3) * 4;

  __shared__ __align__(16) float sbuf[8192];   // 32 KB: score parts [w][j][lane][q]
                                               // reused: PV parts [w][q][256]
  __shared__ __align__(16) float p2[256 * 4];  // 4 KB [k][q]
  __shared__ float rsum_lds[4];

  const int vl = vlen[b];
  const int nj = (vl + 63) >> 6;

  // Wsum = sum(w_v)
  float s0 = w_v[lane] + w_v[lane + 64] + w_v[lane + 128] + w_v[lane + 192];
#pragma unroll
  for (int off = 32; off; off >>= 1) s0 += __shfl_xor(s0, off);
  const float Wsum = s0;

  const float* qp = qs + (size_t)(b * 256 + q0) * 256;   // 4 rows, uniform
  const float* kp = ks_p + (size_t)b * 65536 + lane * 4;
  const int h4b = w * 8;

  float sc[4][4] = {};
  switch (nj) {
    case 1:  score_loop<1>(kp, qp, w_v, h4b, sc); break;
    case 2:  score_loop<2>(kp, qp, w_v, h4b, sc); break;
    case 3:  score_loop<3>(kp, qp, w_v, h4b, sc); break;
    default: score_loop<4>(kp, qp, w_v, h4b, sc); break;
  }

  // write partials: sbuf[((w*4 + j)*64 + lane)*4 + q]  (b128, conflict-free)
#pragma unroll
  for (int j = 0; j < 4; ++j)
    *(float4*)&sbuf[((w * 4 + j) * 64 + lane) * 4] =
        make_float4(sc[j][0], sc[j][1], sc[j][2], sc[j][3]);
  __syncthreads();

  // softmax: waves 0-3, wave q owns q-row q0+q
  if (w < 4) {
    const int q = w;
    float scores[4];
    float mx = -3.4e38f;
#pragma unroll 4
    for (int j = 0; j < nj; ++j) {
      float s = 0.f;
#pragma unroll
      for (int ww = 0; ww < 8; ++ww)
        s += sbuf[((ww * 4 + j) * 64 + lane) * 4 + q];
      float v = Wsum - 2.f * s;
      if (j * 64 + lane >= vl) v = -1000000.0f;
      scores[j] = v;
      mx = fmaxf(mx, v);
    }
#pragma unroll
    for (int off = 32; off; off >>= 1) mx = fmaxf(mx, __shfl_xor(mx, off));
    float sum = 0.f;
#pragma unroll 4
    for (int j = 0; j < nj; ++j) {
      float p = fast_exp2((scores[j] - mx) * LOG2E);
      p2[(j * 64 + lane) * 4 + q] = p;
      sum += p;
    }
#pragma unroll
    for (int off = 32; off; off >>= 1) sum += __shfl_xor(sum, off);
    if (lane == 0) rsum_lds[q] = sum;
  }
  __syncthreads();                        // sbuf reads done; p2/rsum ready

  // PV: wave w takes k == w (mod 8); 4 q-accums per V load; depth-1 prefetch
  float4 acc[4];
#pragma unroll
  for (int q = 0; q < 4; ++q) acc[q] = make_float4(0.f, 0.f, 0.f, 0.f);
  const float* Vb = values + (size_t)b * 65536 + lane * 4;
  if (w < vl) {
    float4 v = *(const float4*)(Vb + (size_t)w * 256);
    for (int k = w; k < vl; k += 8) {
      float4 vn = v;
      if (k + 8 < vl) vn = *(const float4*)(Vb + (size_t)(k + 8) * 256);
      float4 pk = *(const float4*)&p2[k * 4];        // b128 LDS broadcast
      acc[0].x = fmaf(pk.x, v.x, acc[0].x);
      acc[0].y = fmaf(pk.x, v.y, acc[0].y);
      acc[0].z = fmaf(pk.x, v.z, acc[0].z);
      acc[0].w = fmaf(pk.x, v.w, acc[0].w);
      acc[1].x = fmaf(pk.y, v.x, acc[1].x);
      acc[1].y = fmaf(pk.y, v.y, acc[1].y);
      acc[1].z = fmaf(pk.y, v.z, acc[1].z);
      acc[1].w = fmaf(pk.y, v.w, acc[1].w);
      acc[2].x = fmaf(pk.z, v.x, acc[2].x);
      acc[2].y = fmaf(pk.z, v.y, acc[2].y);
      acc[2].z = fmaf(pk.z, v.z, acc[2].z);
      acc[2].w = fmaf(pk.z, v.w, acc[2].w);
      acc[3].x = fmaf(pk.w, v.x, acc[3].x);
      acc[3].y = fmaf(pk.w, v.y, acc[3].y);
      acc[3].z = fmaf(pk.w, v.z, acc[3].z);
      acc[3].w = fmaf(pk.w, v.w, acc[3].w);
      v = vn;
    }
  }
  // PV partials reuse sbuf: [w][q][256]
#pragma unroll
  for (int q = 0; q < 4; ++q)
    *(float4*)&sbuf[(w * 4 + q) * 256 + lane * 4] = acc[q];
  __syncthreads();

  // final reduce: 512 thr x 2 -> 4q x 256d
#pragma unroll
  for (int rep = 0; rep < 2; ++rep) {
    int o = t + rep * 512;
    int q = o >> 8, d = o & 255;
    float s = 0.f;
#pragma unroll
    for (int ww = 0; ww < 8; ++ww) s += sbuf[(ww * 4 + q) * 256 + d];
    out[(size_t)(b * 256 + q0 + q) * 256 + d] = s * fast_rcp(rsum_lds[q]);
  }
}

extern "C" void kernel_launch(void* const* d_in, const int* in_sizes, int n_in,
                              void* d_out, int out_size, void* d_ws, size_t ws_size,
                              hipStream_t stream) {
  const float* queries = (const float*)d_in[0];
  const float* keys    = (const float*)d_in[1];
  const float* values  = (const float*)d_in[2];
  const int*   vlenp   = (const int*)d_in[3];
  const float* W_q     = (const float*)d_in[4];
  const float* W_k     = (const float*)d_in[5];
  const float* w_v     = (const float*)d_in[6];
  float* out = (float*)d_out;

  float* qs   = (float*)d_ws;               // 2 MiB, Eq f32 row-major [m][256]
  float* ks_p = qs + 2048 * 256;            // 2 MiB, Ek f32 packed [b][h/4][k][4]

  dim3 pgrid(8, 32, 2);                     // (n-strips of 32, m-tiles, matrix)
  proj_kernel<<<pgrid, 256, 0, stream>>>(queries, keys, W_q, W_k, vlenp, qs, ks_p);
  attn_kernel<<<512, 512, 0, stream>>>(qs, ks_p, values, vlenp, w_v, out);
}

// Round 18
// 34.674 us; speedup vs baseline: 2.2659x; 1.0367x over previous
//
#include <hip/hip_runtime.h>
#include <hip/hip_bf16.h>

#define LOG2E 1.4426950408889634f
#define C2    (2.0f * LOG2E)

static __device__ __forceinline__ float fast_exp2(float x) {
#if __has_builtin(__builtin_amdgcn_exp2f)
  return __builtin_amdgcn_exp2f(x);
#else
  return exp2f(x);
#endif
}
static __device__ __forceinline__ float fast_rcp(float x) {
#if __has_builtin(__builtin_amdgcn_rcpf)
  return __builtin_amdgcn_rcpf(x);
#else
  return 1.0f / x;
#endif
}

typedef short bf16x8 __attribute__((ext_vector_type(8)));
typedef float f32x4  __attribute__((ext_vector_type(4)));

static __device__ __forceinline__ short f2bf(float x) {  // RNE f32->bf16
  unsigned u = __float_as_uint(x);
  u += 0x7fff + ((u >> 16) & 1);
  return (short)(u >> 16);
}

// ---------------------------------------------------------------------------
// MFMA projections v2 (r17, unchanged).
//   bz=0: qs[q][h] = exp2(C2*(queries@W_q))   f32 row-major (Eq)
//   bz=1: ks_p[((b*64+h/4)*256+k)*4 + h%4] = exp2(C2*(keys@W_k))  (Ek, f32)
// ---------------------------------------------------------------------------
__global__ __launch_bounds__(256, 4) void proj_kernel(
    const float* __restrict__ queries, const float* __restrict__ keys,
    const float* __restrict__ W_q,     const float* __restrict__ W_k,
    const int*   __restrict__ vlen,
    float* __restrict__ qs, float* __restrict__ ks_p)
{
  const int bz = blockIdx.z;
  const float* X = bz ? keys : queries;
  const float* W = bz ? W_k  : W_q;
  const int n0 = blockIdx.x * 32;
  const int m0 = blockIdx.y * 64;

  if (bz == 1) {                      // masked key tiles: skip whole block
    const int vl = vlen[m0 >> 8];
    if ((m0 & 255) >= vl) return;
  }

  const int t = threadIdx.x;
  const int l = t & 63;
  const int w = t >> 6;

  __shared__ short Wp[8 * 2 * 64 * 8];   // [kc][nt][lane][j] bf16, 16 KB

  {
    const int nl = t & 31, ko = t >> 5;
#pragma unroll
    for (int rep = 0; rep < 4; ++rep) {
      const int koct = ko + rep * 8;        // 0..31, k = koct*8 + jj
      const int kc  = koct >> 2;
      const int grp = koct & 3;
      const int nt  = nl >> 4;
      const int ln  = grp * 16 + (nl & 15);
      short w8[8];
#pragma unroll
      for (int jj = 0; jj < 8; ++jj)
        w8[jj] = f2bf(W[(size_t)(koct * 8 + jj) * 256 + n0 + nl]);
      *(bf16x8*)&Wp[((kc * 2 + nt) * 64 + ln) * 8] = *(bf16x8*)w8;
    }
  }
  __syncthreads();

  const int mb   = m0 + w * 16;
  const int row  = mb + (l & 15);
  const int kofs = (l >> 4) * 8;

  f32x4 acc0 = {0.f, 0.f, 0.f, 0.f};
  f32x4 acc1 = {0.f, 0.f, 0.f, 0.f};
#pragma unroll
  for (int kc = 0; kc < 8; ++kc) {
    float4 a0 = *(const float4*)&X[(size_t)row * 256 + kc * 32 + kofs];
    float4 a1 = *(const float4*)&X[(size_t)row * 256 + kc * 32 + kofs + 4];
    bf16x8 af;
    af[0] = f2bf(a0.x); af[1] = f2bf(a0.y); af[2] = f2bf(a0.z); af[3] = f2bf(a0.w);
    af[4] = f2bf(a1.x); af[5] = f2bf(a1.y); af[6] = f2bf(a1.z); af[7] = f2bf(a1.w);
    bf16x8 b0 = *(bf16x8*)&Wp[((kc * 2 + 0) * 64 + l) * 8];
    bf16x8 b1 = *(bf16x8*)&Wp[((kc * 2 + 1) * 64 + l) * 8];
    acc0 = __builtin_amdgcn_mfma_f32_16x16x32_bf16(af, b0, acc0, 0, 0, 0);
    acc1 = __builtin_amdgcn_mfma_f32_16x16x32_bf16(af, b1, acc1, 0, 0, 0);
  }

  const int c = l & 15;
#pragma unroll
  for (int nt = 0; nt < 2; ++nt) {
    const f32x4 acc = nt ? acc1 : acc0;
    const int n = n0 + nt * 16 + c;
#pragma unroll
    for (int j = 0; j < 4; ++j) {
      const int rj = (l >> 4) * 4 + j;
      const float o = fast_exp2(acc[j] * C2);
      if (bz == 0) {
        qs[(size_t)(mb + rj) * 256 + n] = o;
      } else {
        const int b  = mb >> 8;
        const int kl = (mb & 255) + rj;
        ks_p[((size_t)(b * 64 + (n >> 2)) * 256 + kl) * 4 + (n & 3)] = o;
      }
    }
  }
}

// ---------------------------------------------------------------------------
// Score inner loop with PAIRWISE RCP FUSION:
//   w1/(1+x1) + w2/(1+x2) = (w1*t2 + w2*t1) * rcp(t1*t2),  t_i = fma(eq,ek,1)
// Per 2 elems: 6 VALU + 1 rcp (was 4 VALU + 2 rcp) -> trans-pipe load
// halves; issue floor drops ~25%; rcp dep chains halve.  Exact algebra
// (den <= 2^36, finite); wv stays SGPR-uniform.
// Wave = h-eighth (8 h4 iters); kv amortized over 4 q-rows.
// ---------------------------------------------------------------------------
#define SC_PAIR_Q(qv, qi, ca, cb)                                          \
  {                                                                        \
    float t0 = fmaf(qv.ca, kv[j].ca, 1.f);                                 \
    float t1 = fmaf(qv.cb, kv[j].cb, 1.f);                                 \
    float num = fmaf(wv.ca, t1, wv.cb * t0);                               \
    sc[j][qi] = fmaf(num, fast_rcp(t0 * t1), sc[j][qi]);                   \
  }

template <int NJ>
__device__ __forceinline__ void score_loop(
    const float* __restrict__ kp,    // ks_p + b*65536 + lane*4
    const float* __restrict__ qp,    // qs + (b*256+q0)*256 (4 rows)
    const float* __restrict__ wvp, int h4b, float (&sc)[4][4])
{
#pragma unroll 2
  for (int h4 = h4b; h4 < h4b + 8; ++h4) {
    float4 kv[NJ];
#pragma unroll
    for (int j = 0; j < NJ; ++j)
      kv[j] = *(const float4*)(kp + h4 * 1024 + j * 256);
    float4 qv0 = *(const float4*)(qp + 0 * 256 + h4 * 4);  // uniform s_loads
    float4 qv1 = *(const float4*)(qp + 1 * 256 + h4 * 4);
    float4 qv2 = *(const float4*)(qp + 2 * 256 + h4 * 4);
    float4 qv3 = *(const float4*)(qp + 3 * 256 + h4 * 4);
    float4 wv  = *(const float4*)(wvp + h4 * 4);
#pragma unroll
    for (int j = 0; j < NJ; ++j) {
      SC_PAIR_Q(qv0, 0, x, y); SC_PAIR_Q(qv1, 1, x, y);
      SC_PAIR_Q(qv2, 2, x, y); SC_PAIR_Q(qv3, 3, x, y);
      SC_PAIR_Q(qv0, 0, z, w); SC_PAIR_Q(qv1, 1, z, w);
      SC_PAIR_Q(qv2, 2, z, w); SC_PAIR_Q(qv3, 3, z, w);
    }
  }
}

// ---------------------------------------------------------------------------
// Fused scores + softmax + PV (r13/r17 structure, unchanged).
// ---------------------------------------------------------------------------
__global__ __launch_bounds__(512, 4) void attn_kernel(
    const float* __restrict__ qs, const float* __restrict__ ks_p,
    const float* __restrict__ values, const int* __restrict__ vlen,
    const float* __restrict__ w_v, float* __restrict__ out)
{
  const int t    = threadIdx.x;
  const int lane = t & 63;
  const int w    = t >> 6;                 // h-eighth / PV k-parity 0..7
  const int bx   = blockIdx.x;
  const int b    = ((bx & 7) + (bx >> 6)) & 7;
  const int q0   = (bx >> 3) * 4;

  __shared__ __align__(16) float sbuf[8192];   // 32 KB: score parts [w][j][lane][q]
                                               // reused: PV parts [w][q][256]
  __shared__ __align__(16) float p2[256 * 4];  // 4 KB [k][q]
  __shared__ float rsum_lds[4];

  const int vl = vlen[b];
  const int nj = (vl + 63) >> 6;

  // Wsum = sum(w_v)
  float s0 = w_v[lane] + w_v[lane + 64] + w_v[lane + 128] + w_v[lane + 192];
#pragma unroll
  for (int off = 32; off; off >>= 1) s0 += __shfl_xor(s0, off);
  const float Wsum = s0;

  const float* qp = qs + (size_t)(b * 256 + q0) * 256;   // 4 rows, uniform
  const float* kp = ks_p + (size_t)b * 65536 + lane * 4;
  const int h4b = w * 8;

  float sc[4][4] = {};
  switch (nj) {
    case 1:  score_loop<1>(kp, qp, w_v, h4b, sc); break;
    case 2:  score_loop<2>(kp, qp, w_v, h4b, sc); break;
    case 3:  score_loop<3>(kp, qp, w_v, h4b, sc); break;
    default: score_loop<4>(kp, qp, w_v, h4b, sc); break;
  }

  // write partials: sbuf[((w*4 + j)*64 + lane)*4 + q]  (b128, conflict-free)
#pragma unroll
  for (int j = 0; j < 4; ++j)
    *(float4*)&sbuf[((w * 4 + j) * 64 + lane) * 4] =
        make_float4(sc[j][0], sc[j][1], sc[j][2], sc[j][3]);
  __syncthreads();

  // softmax: waves 0-3, wave q owns q-row q0+q
  if (w < 4) {
    const int q = w;
    float scores[4];
    float mx = -3.4e38f;
#pragma unroll 4
    for (int j = 0; j < nj; ++j) {
      float s = 0.f;
#pragma unroll
      for (int ww = 0; ww < 8; ++ww)
        s += sbuf[((ww * 4 + j) * 64 + lane) * 4 + q];
      float v = Wsum - 2.f * s;
      if (j * 64 + lane >= vl) v = -1000000.0f;
      scores[j] = v;
      mx = fmaxf(mx, v);
    }
#pragma unroll
    for (int off = 32; off; off >>= 1) mx = fmaxf(mx, __shfl_xor(mx, off));
    float sum = 0.f;
#pragma unroll 4
    for (int j = 0; j < nj; ++j) {
      float p = fast_exp2((scores[j] - mx) * LOG2E);
      p2[(j * 64 + lane) * 4 + q] = p;
      sum += p;
    }
#pragma unroll
    for (int off = 32; off; off >>= 1) sum += __shfl_xor(sum, off);
    if (lane == 0) rsum_lds[q] = sum;
  }
  __syncthreads();                        // sbuf reads done; p2/rsum ready

  // PV: wave w takes k == w (mod 8); 4 q-accums per V load; depth-1 prefetch
  float4 acc[4];
#pragma unroll
  for (int q = 0; q < 4; ++q) acc[q] = make_float4(0.f, 0.f, 0.f, 0.f);
  const float* Vb = values + (size_t)b * 65536 + lane * 4;
  if (w < vl) {
    float4 v = *(const float4*)(Vb + (size_t)w * 256);
    for (int k = w; k < vl; k += 8) {
      float4 vn = v;
      if (k + 8 < vl) vn = *(const float4*)(Vb + (size_t)(k + 8) * 256);
      float4 pk = *(const float4*)&p2[k * 4];        // b128 LDS broadcast
      acc[0].x = fmaf(pk.x, v.x, acc[0].x);
      acc[0].y = fmaf(pk.x, v.y, acc[0].y);
      acc[0].z = fmaf(pk.x, v.z, acc[0].z);
      acc[0].w = fmaf(pk.x, v.w, acc[0].w);
      acc[1].x = fmaf(pk.y, v.x, acc[1].x);
      acc[1].y = fmaf(pk.y, v.y, acc[1].y);
      acc[1].z = fmaf(pk.y, v.z, acc[1].z);
      acc[1].w = fmaf(pk.y, v.w, acc[1].w);
      acc[2].x = fmaf(pk.z, v.x, acc[2].x);
      acc[2].y = fmaf(pk.z, v.y, acc[2].y);
      acc[2].z = fmaf(pk.z, v.z, acc[2].z);
      acc[2].w = fmaf(pk.z, v.w, acc[2].w);
      acc[3].x = fmaf(pk.w, v.x, acc[3].x);
      acc[3].y = fmaf(pk.w, v.y, acc[3].y);
      acc[3].z = fmaf(pk.w, v.z, acc[3].z);
      acc[3].w = fmaf(pk.w, v.w, acc[3].w);
      v = vn;
    }
  }
  // PV partials reuse sbuf: [w][q][256]
#pragma unroll
  for (int q = 0; q < 4; ++q)
    *(float4*)&sbuf[(w * 4 + q) * 256 + lane * 4] = acc[q];
  __syncthreads();

  // final reduce: 512 thr x 2 -> 4q x 256d
#pragma unroll
  for (int rep = 0; rep < 2; ++rep) {
    int o = t + rep * 512;
    int q = o >> 8, d = o & 255;
    float s = 0.f;
#pragma unroll
    for (int ww = 0; ww < 8; ++ww) s += sbuf[(ww * 4 + q) * 256 + d];
    out[(size_t)(b * 256 + q0 + q) * 256 + d] = s * fast_rcp(rsum_lds[q]);
  }
}

extern "C" void kernel_launch(void* const* d_in, const int* in_sizes, int n_in,
                              void* d_out, int out_size, void* d_ws, size_t ws_size,
                              hipStream_t stream) {
  const float* queries = (const float*)d_in[0];
  const float* keys    = (const float*)d_in[1];
  const float* values  = (const float*)d_in[2];
  const int*   vlenp   = (const int*)d_in[3];
  const float* W_q     = (const float*)d_in[4];
  const float* W_k     = (const float*)d_in[5];
  const float* w_v     = (const float*)d_in[6];
  float* out = (float*)d_out;

  float* qs   = (float*)d_ws;               // 2 MiB, Eq f32 row-major [m][256]
  float* ks_p = qs + 2048 * 256;            // 2 MiB, Ek f32 packed [b][h/4][k][4]

  dim3 pgrid(8, 32, 2);                     // (n-strips of 32, m-tiles, matrix)
  proj_kernel<<<pgrid, 256, 0, stream>>>(queries, keys, W_q, W_k, vlenp, qs, ks_p);
  attn_kernel<<<512, 512, 0, stream>>>(qs, ks_p, values, vlenp, w_v, out);
}